// Round 4
// baseline (63.284 us; speedup 1.0000x reference)
//
#include <hip/hip_runtime.h>
#include <hip/hip_cooperative_groups.h>

namespace cg = cooperative_groups;

#define BB 16
#define HH 2048
#define NN 1024
#define DD 2048

// One fused cooperative kernel. Grid = 256 blocks x 512 threads, 1 block/CU.
// Block g owns output rows n = g + 256*r (r=0..3) for all 16 batches.
// Blocks 0..15 additionally run phase1 (softmax+scatter) for batch = g.
__global__ __launch_bounds__(512) void ot_fused(const int* __restrict__ z,
                                                const float* __restrict__ Fm,
                                                const float* __restrict__ Vm,
                                                const float* __restrict__ Wm,
                                                int* __restrict__ hdr,
                                                float* __restrict__ wsT,
                                                float* __restrict__ out) {
    __shared__ float4 rows[8][DD / 4];   // 64 KB: j = r*2 + m (m:0=V,1=F)
    __shared__ int    zsh[HH];           // 8 KB  (phase1 only)
    __shared__ float  w1s[DD];           // 8 KB  (phase1 only)
    __shared__ float  w2s[DD];           // 8 KB  (phase1 only)
    __shared__ float  wsh[DD];           // 8 KB  (phase1 only)
    __shared__ float  redm[8], redt[8];
    __shared__ float  red[8][8][BB];     // 4 KB
    __shared__ float  fin[8][BB];

    const int tid  = threadIdx.x;
    const int lane = tid & 63;
    const int w    = tid >> 6;           // wave 0..7
    const int g    = blockIdx.x;

    // ---- issue V/F prefetch into registers (HBM latency hides under phase1) ----
    float4 pf[8];
    {
        const int r = w >> 1, m = w & 1;
        const float4* __restrict__ src =
            (const float4*)((m ? Fm : Vm) + (size_t)(g + 256 * r) * DD);
#pragma unroll
        for (int k = 0; k < 8; ++k) pf[k] = src[k * 64 + lane];
    }

    // ---- phase1: blocks 0..15, batch b = g ----
    if (g < BB) {
        const int b = g;
        ((int4*)zsh)[tid] = ((const int4*)(z + (size_t)b * HH))[tid];
        wsh[tid] = 0.f; wsh[tid + 512] = 0.f; wsh[tid + 1024] = 0.f; wsh[tid + 1536] = 0.f;
        __syncthreads();
        const int d1 = zsh[HH - 1];          // [0, NN)
        const int d2 = zsh[HH - 2] + NN;     // [NN, DD)
        ((float4*)w1s)[tid] = ((const float4*)(Wm + (size_t)d1 * DD))[tid];
        ((float4*)w2s)[tid] = ((const float4*)(Wm + (size_t)d2 * DD))[tid];
        __syncthreads();

        float s[4], e[4];
        float mloc = -1e30f;
#pragma unroll
        for (int k = 0; k < 4; ++k) {
            const int h  = 4 * tid + k;
            const int zh = zsh[h];
            float sv = w1s[zh] + w2s[zh];
            if (h > 0) { const int zp = zsh[h - 1] + NN; sv += w1s[zp] + w2s[zp]; }
            s[k] = sv; mloc = fmaxf(mloc, sv);
        }
#pragma unroll
        for (int off = 32; off > 0; off >>= 1) mloc = fmaxf(mloc, __shfl_xor(mloc, off));
        if (lane == 0) redm[w] = mloc;
        __syncthreads();
        float mx = redm[0];
#pragma unroll
        for (int i = 1; i < 8; ++i) mx = fmaxf(mx, redm[i]);

        float t = 0.f;
#pragma unroll
        for (int k = 0; k < 4; ++k) { e[k] = __expf(s[k] - mx); t += e[k]; }
#pragma unroll
        for (int off = 32; off > 0; off >>= 1) t += __shfl_xor(t, off);
        if (lane == 0) redt[w] = t;
        __syncthreads();
        float tot = 0.f;
#pragma unroll
        for (int i = 0; i < 8; ++i) tot += redt[i];
        const float inv = 1.f / tot;

#pragma unroll
        for (int k = 0; k < 4; ++k) {
            const int h = 4 * tid + k;
            atomicAdd(&wsh[zsh[h]], e[k]);
            if (h > 0) atomicAdd(&wsh[zsh[h - 1] + NN], e[k]);
        }
        __syncthreads();

        float4 o;
        o.x = wsh[4 * tid + 0] * inv;
        o.y = wsh[4 * tid + 1] * inv;
        o.z = wsh[4 * tid + 2] * inv;
        o.w = wsh[4 * tid + 3] * inv;
        ((float4*)wsT)[(size_t)tid * BB + b] = o;   // layout [dg][b] float4
        if (tid == 0) { hdr[b] = d1; hdr[BB + b] = d2; }
        __threadfence();
    }

    // ---- land prefetched rows in LDS, then grid-wide sync ----
#pragma unroll
    for (int k = 0; k < 8; ++k) rows[w][k * 64 + lane] = pf[k];
    cg::this_grid().sync();

    // ---- compute: thread (s = tid>>4, b = lane&15) holds ws[dg = s+32i][b] ----
    const int b = lane & 15;
    const int s = tid >> 4;              // 0..31

    float4 wsr[16];
#pragma unroll
    for (int i = 0; i < 16; ++i)
        wsr[i] = ((const float4*)wsT)[(size_t)(s + 32 * i) * BB + b];

    float part[8];
#pragma unroll
    for (int j = 0; j < 8; ++j) part[j] = 0.f;

#pragma unroll
    for (int i = 0; i < 16; ++i) {
        const int dg = s + 32 * i;
#pragma unroll
        for (int j = 0; j < 8; ++j) {
            float4 rv = rows[j][dg];     // 16-lane broadcast read (bank-free)
            part[j] += rv.x * wsr[i].x + rv.y * wsr[i].y
                     + rv.z * wsr[i].z + rv.w * wsr[i].w;
        }
    }

    // reduce over s: q = s&3 via shuffle, wave index via LDS
#pragma unroll
    for (int j = 0; j < 8; ++j) {
        float p = part[j];
        p += __shfl_xor(p, 16);
        p += __shfl_xor(p, 32);
        part[j] = p;
    }
    if (lane < 16) {
#pragma unroll
        for (int j = 0; j < 8; ++j) red[j][w][lane] = part[j];
    }
    __syncthreads();

    if (tid < 128) {
        const int j = tid >> 4, bb = tid & 15;
        float sum = 0.f;
#pragma unroll
        for (int ww = 0; ww < 8; ++ww) sum += red[j][ww][bb];
        fin[j][bb] = sum;
    }
    __syncthreads();

    if (tid < 64) {
        const int r  = tid >> 4, bb = tid & 15;
        const int n  = g + 256 * r;
        float A  = fin[2 * r][bb];
        float Fv = fin[2 * r + 1][bb];
        const float* __restrict__ Ff = (const float*)&rows[2 * r + 1][0];
        Fv += Ff[hdr[bb]] + Ff[hdr[BB + bb]];
        out[(size_t)bb * NN + n]            = A + Fv;   // xi
        out[(size_t)(BB + bb) * NN + n]     = A;        // xi_A
        out[(size_t)(2 * BB + bb) * NN + n] = Fv;       // xi_F
    }
}

extern "C" void kernel_launch(void* const* d_in, const int* in_sizes, int n_in,
                              void* d_out, int out_size, void* d_ws, size_t ws_size,
                              hipStream_t stream) {
    const int*   z  = (const int*)d_in[0];
    const float* Fm = (const float*)d_in[1];
    const float* Vm = (const float*)d_in[2];
    const float* Wm = (const float*)d_in[3];
    float* out = (float*)d_out;

    int*   hdr = (int*)d_ws;
    float* wsT = (float*)((char*)d_ws + 128);

    void* args[] = {(void*)&z, (void*)&Fm, (void*)&Vm, (void*)&Wm,
                    (void*)&hdr, (void*)&wsT, (void*)&out};
    hipLaunchCooperativeKernel((const void*)ot_fused, dim3(256), dim3(512),
                               args, 0, stream);
}

// Round 5
// 24.353 us; speedup vs baseline: 2.5987x; 2.5987x over previous
//
#include <hip/hip_runtime.h>

#define BB 16
#define HH 2048
#define NN 1024
#define DD 2048
#define DG (DD / 4)   // 512 d-groups of 4

// Workspace: int hdr[32] (d1[16], d2[16]); pad to 128 B; then
// wsB[DG][BB] uint2 — 4 consecutive d packed as bf16x4 per batch (64 KB).

__device__ __forceinline__ unsigned short f2bf(float f) {
    unsigned u = __float_as_uint(f);
    u += 0x7fffu + ((u >> 16) & 1u);   // round-to-nearest-even
    return (unsigned short)(u >> 16);
}

// Phase 1: per-batch scores -> softmax -> scatter weighted_sum.
// One block per batch, 1024 threads (16 waves).
__global__ __launch_bounds__(1024) void ot_phase1(const int* __restrict__ z,
                                                  const float* __restrict__ W,
                                                  int* __restrict__ hdr,
                                                  uint2* __restrict__ wsB) {
    __shared__ int   zsh[HH];
    __shared__ float w1s[DD];
    __shared__ float w2s[DD];
    __shared__ float wsh[DD];
    __shared__ float redm[16], redt[16];

    const int b    = blockIdx.x;
    const int tid  = threadIdx.x;
    const int lane = tid & 63;
    const int wid  = tid >> 6;

    // broadcast-load the z-row tail first: d1,d2 available with no barrier
    const int4 zt = ((const int4*)(z + (size_t)b * HH))[DG - 1];  // z[2044..2047]
    const int d1 = zt.w;          // z[H-1] in [0, NN)
    const int d2 = zt.z + NN;     // z[H-2]+N in [NN, DD)

    // issue the two W-row loads immediately (hide HBM latency under staging)
    float4 wv;
    if (tid < 512) wv = ((const float4*)(W + (size_t)d1 * DD))[tid];
    else           wv = ((const float4*)(W + (size_t)d2 * DD))[tid - 512];

    ((int2*)zsh)[tid] = ((const int2*)(z + (size_t)b * HH))[tid];
    wsh[tid] = 0.f; wsh[tid + 1024] = 0.f;
    if (tid < 512) ((float4*)w1s)[tid] = wv;
    else           ((float4*)w2s)[tid - 512] = wv;
    __syncthreads();

    // thread owns h0 = 2*tid, h1 = 2*tid+1
    const int h0 = 2 * tid, h1 = h0 + 1;
    const int z0 = zsh[h0], z1 = zsh[h1];
    const int p0 = (h0 > 0) ? zsh[h0 - 1] + NN : 0;
    const int p1 = z0 + NN;

    float s0 = w1s[z0] + w2s[z0];
    if (h0 > 0) s0 += w1s[p0] + w2s[p0];
    float s1 = w1s[z1] + w2s[z1] + w1s[p1] + w2s[p1];

    float m = fmaxf(s0, s1);
#pragma unroll
    for (int off = 32; off > 0; off >>= 1) m = fmaxf(m, __shfl_xor(m, off));
    if (lane == 0) redm[wid] = m;
    __syncthreads();
    float mx = redm[0];
#pragma unroll
    for (int i = 1; i < 16; ++i) mx = fmaxf(mx, redm[i]);

    const float e0 = __expf(s0 - mx);
    const float e1 = __expf(s1 - mx);
    float t = e0 + e1;
#pragma unroll
    for (int off = 32; off > 0; off >>= 1) t += __shfl_xor(t, off);
    if (lane == 0) redt[wid] = t;
    __syncthreads();
    float tot = 0.f;
#pragma unroll
    for (int i = 0; i < 16; ++i) tot += redt[i];
    const float inv = 1.f / tot;

    atomicAdd(&wsh[z0], e0);
    if (h0 > 0) atomicAdd(&wsh[p0], e0);
    atomicAdd(&wsh[z1], e1);
    atomicAdd(&wsh[p1], e1);
    __syncthreads();

    if (tid < DG) {
        uint2 p;
        p.x = (unsigned)f2bf(wsh[4 * tid + 0] * inv)
            | ((unsigned)f2bf(wsh[4 * tid + 1] * inv) << 16);
        p.y = (unsigned)f2bf(wsh[4 * tid + 2] * inv)
            | ((unsigned)f2bf(wsh[4 * tid + 3] * inv) << 16);
        wsB[(size_t)tid * BB + b] = p;
    }
    if (tid == 0) { hdr[b] = d1; hdr[BB + b] = d2; }
}

// Phase 2: block g computes rows n = 4g..4g+3 for all 16 batches.
// Thread (s = tid>>4 in 0..31, b = tid&15). ws kept packed in 32 VGPRs.
__global__ __launch_bounds__(512, 4) void ot_phase2(const float* __restrict__ V,
                                                    const float* __restrict__ F,
                                                    const int* __restrict__ hdr,
                                                    const uint2* __restrict__ wsB,
                                                    float* __restrict__ out) {
    const int tid  = threadIdx.x;
    const int lane = tid & 63;
    const int w    = tid >> 6;
    const int b    = lane & 15;
    const int s    = tid >> 4;            // 0..31
    const int g    = blockIdx.x;

    uint2 wsr[16];
#pragma unroll
    for (int i = 0; i < 16; ++i) wsr[i] = wsB[(size_t)(s + 32 * i) * BB + b];

    const float4* __restrict__ Vr0 = (const float4*)(V + (size_t)(4 * g + 0) * DD);
    const float4* __restrict__ Vr1 = (const float4*)(V + (size_t)(4 * g + 1) * DD);
    const float4* __restrict__ Vr2 = (const float4*)(V + (size_t)(4 * g + 2) * DD);
    const float4* __restrict__ Vr3 = (const float4*)(V + (size_t)(4 * g + 3) * DD);
    const float4* __restrict__ Fr0 = (const float4*)(F + (size_t)(4 * g + 0) * DD);
    const float4* __restrict__ Fr1 = (const float4*)(F + (size_t)(4 * g + 1) * DD);
    const float4* __restrict__ Fr2 = (const float4*)(F + (size_t)(4 * g + 2) * DD);
    const float4* __restrict__ Fr3 = (const float4*)(F + (size_t)(4 * g + 3) * DD);

    float acc[8];
#pragma unroll
    for (int j = 0; j < 8; ++j) acc[j] = 0.f;

#pragma unroll
    for (int it = 0; it < 16; ++it) {
        const int dg = s + 32 * it;
        const uint2 p = wsr[it];
        const float s0 = __uint_as_float(p.x << 16);
        const float s1 = __uint_as_float(p.x & 0xffff0000u);
        const float s2 = __uint_as_float(p.y << 16);
        const float s3 = __uint_as_float(p.y & 0xffff0000u);
        float4 v0 = Vr0[dg], v1 = Vr1[dg], v2 = Vr2[dg], v3 = Vr3[dg];
        float4 f0 = Fr0[dg], f1 = Fr1[dg], f2 = Fr2[dg], f3 = Fr3[dg];
        acc[0] += v0.x * s0 + v0.y * s1 + v0.z * s2 + v0.w * s3;
        acc[1] += f0.x * s0 + f0.y * s1 + f0.z * s2 + f0.w * s3;
        acc[2] += v1.x * s0 + v1.y * s1 + v1.z * s2 + v1.w * s3;
        acc[3] += f1.x * s0 + f1.y * s1 + f1.z * s2 + f1.w * s3;
        acc[4] += v2.x * s0 + v2.y * s1 + v2.z * s2 + v2.w * s3;
        acc[5] += f2.x * s0 + f2.y * s1 + f2.z * s2 + f2.w * s3;
        acc[6] += v3.x * s0 + v3.y * s1 + v3.z * s2 + v3.w * s3;
        acc[7] += f3.x * s0 + f3.y * s1 + f3.z * s2 + f3.w * s3;
    }

    // reduce over s-quarters within the wave (lanes b, b+16, b+32, b+48)
#pragma unroll
    for (int j = 0; j < 8; ++j) {
        float p = acc[j];
        p += __shfl_xor(p, 16);
        p += __shfl_xor(p, 32);
        acc[j] = p;
    }

    __shared__ float red[8][8][BB];
    if (lane < 16) {
#pragma unroll
        for (int j = 0; j < 8; ++j) red[j][w][b] = acc[j];
    }
    __syncthreads();

    if (tid < 64) {
        const int r = tid >> 4, bb = tid & 15;
        float A = 0.f, Fv = 0.f;
#pragma unroll
        for (int ww = 0; ww < 8; ++ww) {
            A  += red[2 * r + 0][ww][bb];
            Fv += red[2 * r + 1][ww][bb];
        }
        const int n = 4 * g + r;
        const float* __restrict__ Fr = F + (size_t)n * DD;
        Fv += Fr[hdr[bb]] + Fr[hdr[BB + bb]];
        out[(size_t)bb * NN + n]            = A + Fv;   // xi
        out[(size_t)(BB + bb) * NN + n]     = A;        // xi_A
        out[(size_t)(2 * BB + bb) * NN + n] = Fv;       // xi_F
    }
}

extern "C" void kernel_launch(void* const* d_in, const int* in_sizes, int n_in,
                              void* d_out, int out_size, void* d_ws, size_t ws_size,
                              hipStream_t stream) {
    const int*   z  = (const int*)d_in[0];
    const float* Fm = (const float*)d_in[1];
    const float* Vm = (const float*)d_in[2];
    const float* Wm = (const float*)d_in[3];
    float* out = (float*)d_out;

    int*   hdr = (int*)d_ws;
    uint2* wsB = (uint2*)((char*)d_ws + 128);

    ot_phase1<<<BB, 1024, 0, stream>>>(z, Wm, hdr, wsB);
    ot_phase2<<<NN / 4, 512, 0, stream>>>(Vm, Fm, hdr, wsB, out);
}